// Round 5
// baseline (727.830 us; speedup 1.0000x reference)
//
#include <hip/hip_runtime.h>

#define NN 100000
#define NE 1600000
#define SCAN_BLK 2048
#define NSB ((NN + SCAN_BLK - 1) / SCAN_BLK)   // 49 blocks
#define NBUCK ((NN + 63) / 64)                 // 1563 coarse buckets (64 nodes each)

// ---------------- int degree histogram ----------------
__global__ __launch_bounds__(256) void hist_kernel(const int* __restrict__ dst,
                                                   int* __restrict__ hist) {
    int e = blockIdx.x * 256 + threadIdx.x;
    if (e < NE) atomicAdd(&hist[dst[e]], 1);
}

// ---------------- exclusive scan, stage 1: per-block ----------------
__global__ __launch_bounds__(256) void scan1_kernel(int* __restrict__ data,
                                                    int* __restrict__ bsums) {
    __shared__ int s[256];
    int bid = blockIdx.x, tid = threadIdx.x;
    int base = bid * SCAN_BLK + tid * 8;
    int v[8];
    int sum = 0;
#pragma unroll
    for (int t = 0; t < 8; t++) {
        int idx = base + t;
        v[t] = (idx < NN) ? data[idx] : 0;
        sum += v[t];
    }
    s[tid] = sum;
    __syncthreads();
    for (int off = 1; off < 256; off <<= 1) {           // Hillis-Steele inclusive
        int val = (tid >= off) ? s[tid - off] : 0;
        __syncthreads();
        s[tid] += val;
        __syncthreads();
    }
    int excl = s[tid] - sum;
    if (tid == 255) bsums[bid] = s[255];
    int run = excl;
#pragma unroll
    for (int t = 0; t < 8; t++) {
        int idx = base + t;
        if (idx < NN) data[idx] = run;
        run += v[t];
    }
}

// ---------------- scan stage 2: single wave scans block sums ----------------
__global__ __launch_bounds__(64) void scan2_kernel(int* __restrict__ bsums) {
    int tid = threadIdx.x;
    int orig = (tid < NSB) ? bsums[tid] : 0;
    int v = orig;
    for (int off = 1; off < 64; off <<= 1) {
        int n = __shfl_up(v, off, 64);
        if (tid >= off) v += n;
    }
    if (tid < NSB) bsums[tid] = v - orig;               // exclusive
}

// ---------------- scan stage 3: add block offsets; seed bucket cursors ----------------
__global__ __launch_bounds__(256) void scan3_kernel(int* __restrict__ rowptr,
                                                    const int* __restrict__ bsums,
                                                    int* __restrict__ bcur) {
    int i = blockIdx.x * 256 + threadIdx.x;
    if (i < NN) {
        int v = rowptr[i] + bsums[i / SCAN_BLK];
        rowptr[i] = v;
        if ((i & 63) == 0) bcur[i >> 6] = v;            // bucket b starts at rowptr[b*64]
    }
    if (i == 0) rowptr[NN] = NE;
}

// ---------------- bucket pass 1: coarse scatter (dst>>6), packed payload ----------------
// Write frontier = NBUCK line tails (~100 KB) -> L2-resident, full-line writebacks.
__global__ __launch_bounds__(256) void bucket_scatter_kernel(const int* __restrict__ src,
                                                             const int* __restrict__ dst,
                                                             int* __restrict__ bcur,
                                                             int* __restrict__ tmp) {
    int e = blockIdx.x * 256 + threadIdx.x;
    if (e < NE) {
        int d = dst[e];
        int p = atomicAdd(&bcur[d >> 6], 1);
        tmp[p] = src[e] | ((d & 63) << 17);             // NN < 2^17
    }
}

// ---------------- bucket pass 2: fine placement via LDS cursors ----------------
// One block per bucket. Sequential tmp reads; esrc writes confined to a ~4 KB
// window; cursors live in LDS (no global atomics).
__global__ __launch_bounds__(256) void bucket_place_kernel(const int* __restrict__ rowptr,
                                                           const int* __restrict__ tmp,
                                                           int* __restrict__ esrc) {
    __shared__ int lcur[64];
    int b = blockIdx.x, tid = threadIdx.x;
    int lo = b * 64;
    if (tid < 64) {
        int node = lo + tid;
        lcur[tid] = (node < NN) ? rowptr[node] : NE;
    }
    __syncthreads();
    int beg = rowptr[lo];
    int end = rowptr[(lo + 64 <= NN) ? lo + 64 : NN];
    for (int e = beg + tid; e < end; e += 256) {
        int v = tmp[e];
        int p = atomicAdd(&lcur[v >> 17], 1);
        esrc[p] = v & 0x1FFFF;
    }
}

// ---------------- gather-aggregate: one wave per node, mean fused ----------------
template <int K>
__global__ __launch_bounds__(256) void aggregate_kernel(const float* __restrict__ feat,
                                                        const int* __restrict__ rowptr,
                                                        const int* __restrict__ esrc,
                                                        float* __restrict__ agg) {
    int node = blockIdx.x * 4 + (threadIdx.x >> 6);
    int lane = threadIdx.x & 63;
    if (node >= NN) return;
    int beg = rowptr[node], end = rowptr[node + 1];

    float acc0 = 0.0f, acc1 = 0.0f;
    int e = beg;
    for (; e + 3 < end; e += 4) {                       // 4 edges in flight
        int s0 = esrc[e], s1 = esrc[e + 1], s2 = esrc[e + 2], s3 = esrc[e + 3];
        acc0 += feat[s0 * K + lane];
        acc0 += feat[s1 * K + lane];
        acc0 += feat[s2 * K + lane];
        acc0 += feat[s3 * K + lane];
        if (K == 128) {
            acc1 += feat[s0 * K + 64 + lane];
            acc1 += feat[s1 * K + 64 + lane];
            acc1 += feat[s2 * K + 64 + lane];
            acc1 += feat[s3 * K + 64 + lane];
        }
    }
    for (; e < end; e++) {
        int s = esrc[e];
        acc0 += feat[s * K + lane];
        if (K == 128) acc1 += feat[s * K + 64 + lane];
    }
    float inv = 1.0f / fmaxf((float)(end - beg), 1.0f);
    agg[node * K + lane] = acc0 * inv;
    if (K == 128) agg[node * K + 64 + lane] = acc1 * inv;
}

// ---------------- fused dual-input tiled GEMM ----------------
// out[n, 0:128] = A1[n,0:KA] @ Wa.T + A2[n,0:KB] @ Wb.T + bias   (+ReLU)
// Block tile: 128 nodes x 128 outputs. 256 threads, 8x8 micro-tile each,
// split 4+4 so LDS reads alias at most 2-way (free per m136).
// A2/out deliberately NOT __restrict__: layer 2 is in-place on d_out (each
// block reads only its own 128 rows; stores happen only in the epilogue).
template <int KA, int KB, bool RELU>
__global__ __launch_bounds__(256, 4) void gemm_kernel(const float* __restrict__ A1,
                                                      const float* A2,
                                                      const float* __restrict__ Wa,
                                                      const float* __restrict__ Wb,
                                                      const float* __restrict__ bias,
                                                      float* out) {
    __shared__ float As[32][128];
    __shared__ float Bs[32][128];

    const int t = threadIdx.x;
    const int base = blockIdx.x * 128;
    const int half = t & 1;        // which 16-k half this thread stages
    const int srow = t >> 1;       // staging row: node-in-tile / output j
    const int ni = t & 15;
    const int ji = t >> 4;

    float acc[8][8];
#pragma unroll
    for (int i = 0; i < 8; i++)
#pragma unroll
        for (int j = 0; j < 8; j++) acc[i][j] = 0.0f;

    const int NCH = (KA + KB) / 32;
#pragma unroll
    for (int c = 0; c < NCH; ++c) {
        const bool inA = (c * 32) < KA;
        const float* Ap = inA ? A1 : A2;
        const float* Wp = inA ? Wa : Wb;
        const int K  = inA ? KA : KB;
        const int kb = inA ? c * 32 : c * 32 - KA;

        __syncthreads();
        {
            int gn = base + srow;
            if (gn > NN - 1) gn = NN - 1;               // clamp: tail rows discarded later
            const float* ar = Ap + (size_t)gn * K + kb + half * 16;
            const float* wr = Wp + (size_t)srow * K + kb + half * 16;
#pragma unroll
            for (int u = 0; u < 4; ++u) {
                float4 av = *(const float4*)(ar + u * 4);
                float4 wv = *(const float4*)(wr + u * 4);
                int k0 = half * 16 + u * 4;
                As[k0 + 0][srow] = av.x; As[k0 + 1][srow] = av.y;
                As[k0 + 2][srow] = av.z; As[k0 + 3][srow] = av.w;
                Bs[k0 + 0][srow] = wv.x; Bs[k0 + 1][srow] = wv.y;
                Bs[k0 + 2][srow] = wv.z; Bs[k0 + 3][srow] = wv.w;
            }
        }
        __syncthreads();

#pragma unroll 4
        for (int k = 0; k < 32; ++k) {
            float4 a0 = *(const float4*)&As[k][ni * 4];
            float4 a1 = *(const float4*)&As[k][64 + ni * 4];
            float4 b0 = *(const float4*)&Bs[k][ji * 4];
            float4 b1 = *(const float4*)&Bs[k][64 + ji * 4];
            float a[8] = {a0.x, a0.y, a0.z, a0.w, a1.x, a1.y, a1.z, a1.w};
            float b[8] = {b0.x, b0.y, b0.z, b0.w, b1.x, b1.y, b1.z, b1.w};
#pragma unroll
            for (int i = 0; i < 8; ++i)
#pragma unroll
                for (int j = 0; j < 8; ++j) acc[i][j] += a[i] * b[j];
        }
    }

    float4 bz0 = *(const float4*)(bias + ji * 4);
    float4 bz1 = *(const float4*)(bias + 64 + ji * 4);
#pragma unroll
    for (int i = 0; i < 8; ++i) {
        int r = base + (i < 4 ? ni * 4 + i : 64 + ni * 4 + (i - 4));
        if (r >= NN) continue;
        float4 o0, o1;
        o0.x = acc[i][0] + bz0.x; o0.y = acc[i][1] + bz0.y;
        o0.z = acc[i][2] + bz0.z; o0.w = acc[i][3] + bz0.w;
        o1.x = acc[i][4] + bz1.x; o1.y = acc[i][5] + bz1.y;
        o1.z = acc[i][6] + bz1.z; o1.w = acc[i][7] + bz1.w;
        if (RELU) {
            o0.x = fmaxf(o0.x, 0.0f); o0.y = fmaxf(o0.y, 0.0f);
            o0.z = fmaxf(o0.z, 0.0f); o0.w = fmaxf(o0.w, 0.0f);
            o1.x = fmaxf(o1.x, 0.0f); o1.y = fmaxf(o1.y, 0.0f);
            o1.z = fmaxf(o1.z, 0.0f); o1.w = fmaxf(o1.w, 0.0f);
        }
        float* op = out + (size_t)r * 128;
        *(float4*)(op + ji * 4) = o0;
        *(float4*)(op + 64 + ji * 4) = o1;
    }
}

extern "C" void kernel_launch(void* const* d_in, const int* in_sizes, int n_in,
                              void* d_out, int out_size, void* d_ws, size_t ws_size,
                              hipStream_t stream) {
    const float* x   = (const float*)d_in[0];
    const int*   ei  = (const int*)d_in[1];
    const float* W1l = (const float*)d_in[2];
    const float* W1r = (const float*)d_in[3];
    const float* b1  = (const float*)d_in[4];
    const float* W2l = (const float*)d_in[5];
    const float* W2r = (const float*)d_in[6];
    const float* b2  = (const float*)d_in[7];
    float* out = (float*)d_out;

    const int* src = ei;        // edge_index[0]
    const int* dst = ei + NE;   // edge_index[1]

    // workspace layout
    char* ws = (char*)d_ws;
    int*   rowptr = (int*)ws;                        // (NN+1) ints      [0, 401408)
    int*   esrc   = (int*)(ws + 401408);             // NE ints          [401408, 6801408)
    float* agg    = (float*)(ws + 6803456);          // NN*128 floats    [6803456, +51.2MB)
    // transients, dead before the agg region is written:
    int* bsums = (int*)(ws + 6803456 + 409600);      // NSB ints (aliases agg)
    int* bcur  = (int*)(ws + 6803456 + 409600 + 4096);  // NBUCK ints (aliases agg)
    int* tmp   = (int*)(ws + 6803456 + 26214400);    // NE ints; aliases agg's layer-2-only
                                                     // upper half (first write: aggregate<128>)
    const int NB  = (NN + 255) / 256;
    const int NBT = (NN + 127) / 128;                // gemm tiles

    // ---- build CSR (edge list sorted by dst), shared by both layers ----
    hipMemsetAsync(rowptr, 0, 401408, stream);
    hist_kernel<<<(NE + 255) / 256, 256, 0, stream>>>(dst, rowptr);
    scan1_kernel<<<NSB, 256, 0, stream>>>(rowptr, bsums);
    scan2_kernel<<<1, 64, 0, stream>>>(bsums);
    scan3_kernel<<<NB, 256, 0, stream>>>(rowptr, bsums, bcur);
    bucket_scatter_kernel<<<(NE + 255) / 256, 256, 0, stream>>>(src, dst, bcur, tmp);
    bucket_place_kernel<<<NBUCK, 256, 0, stream>>>(rowptr, tmp, esrc);

    // ---- layer 1: out = relu(mean(agg) @ W1l.T + x @ W1r.T + b1) ----
    aggregate_kernel<64><<<NN / 4, 256, 0, stream>>>(x, rowptr, esrc, agg);
    gemm_kernel<64, 64, true><<<NBT, 256, 0, stream>>>(agg, x, W1l, W1r, b1, out);

    // ---- layer 2: out = mean(agg2) @ W2l.T + h @ W2r.T + b2  (h = out, in-place) ----
    aggregate_kernel<128><<<NN / 4, 256, 0, stream>>>(out, rowptr, esrc, agg);
    gemm_kernel<128, 128, false><<<NBT, 256, 0, stream>>>(agg, out, W2l, W2r, b2, out);
}

// Round 6
// 533.379 us; speedup vs baseline: 1.3646x; 1.3646x over previous
//
#include <hip/hip_runtime.h>

#define NN 100000
#define NE 1600000
#define SCAN_BLK 2048
#define NSB ((NN + SCAN_BLK - 1) / SCAN_BLK)   // 49 blocks for rowptr scan

#define BSH 9                                  // bucket shift: 512 nodes/bucket
#define NBUCK2 ((NN + 511) / 512)              // 196 coarse buckets
#define CHUNK 8192                             // edges per partition block
#define NCHK ((NE + CHUNK - 1) / CHUNK)        // 196 chunks
#define L2T (NBUCK2 * NCHK)                    // histogram matrix size (38416)

// ---------------- int degree histogram (100K addresses -> low contention) ----------------
__global__ __launch_bounds__(256) void hist_kernel(const int* __restrict__ dst,
                                                   int* __restrict__ hist) {
    int e = blockIdx.x * 256 + threadIdx.x;
    if (e < NE) atomicAdd(&hist[dst[e]], 1);
}

// ---------------- per-chunk bucket histogram (LDS, no global atomics) ----------------
__global__ __launch_bounds__(256) void hist2_kernel(const int* __restrict__ dst,
                                                    int* __restrict__ histm) {
    __shared__ int lh[256];
    int blk = blockIdx.x, tid = threadIdx.x;
    lh[tid] = 0;
    __syncthreads();
    int base = blk * CHUNK;
#pragma unroll
    for (int t = 0; t < CHUNK / 256; t++) {
        int e = base + t * 256 + tid;
        if (e < NE) atomicAdd(&lh[dst[e] >> BSH], 1);
    }
    __syncthreads();
    if (tid < NBUCK2) histm[tid * NCHK + blk] = lh[tid];   // bucket-major
}

// ---------------- exclusive scan, stage 1: per-block (length L) ----------------
__global__ __launch_bounds__(256) void scan1_kernel(int* __restrict__ data,
                                                    int* __restrict__ bsums, int L) {
    __shared__ int s[256];
    int bid = blockIdx.x, tid = threadIdx.x;
    int base = bid * SCAN_BLK + tid * 8;
    int v[8];
    int sum = 0;
#pragma unroll
    for (int t = 0; t < 8; t++) {
        int idx = base + t;
        v[t] = (idx < L) ? data[idx] : 0;
        sum += v[t];
    }
    s[tid] = sum;
    __syncthreads();
    for (int off = 1; off < 256; off <<= 1) {           // Hillis-Steele inclusive
        int val = (tid >= off) ? s[tid - off] : 0;
        __syncthreads();
        s[tid] += val;
        __syncthreads();
    }
    int excl = s[tid] - sum;
    if (tid == 255) bsums[bid] = s[255];
    int run = excl;
#pragma unroll
    for (int t = 0; t < 8; t++) {
        int idx = base + t;
        if (idx < L) data[idx] = run;
        run += v[t];
    }
}

// ---------------- scan stage 2: single wave scans n<=64 block sums ----------------
__global__ __launch_bounds__(64) void scan2_kernel(int* __restrict__ bsums, int n) {
    int tid = threadIdx.x;
    int orig = (tid < n) ? bsums[tid] : 0;
    int v = orig;
    for (int off = 1; off < 64; off <<= 1) {
        int nb = __shfl_up(v, off, 64);
        if (tid >= off) v += nb;
    }
    if (tid < n) bsums[tid] = v - orig;                 // exclusive
}

// ---------------- scan stage 3 (rowptr): add block offsets, set tail ----------------
__global__ __launch_bounds__(256) void scan3_kernel(int* __restrict__ rowptr,
                                                    const int* __restrict__ bsums) {
    int i = blockIdx.x * 256 + threadIdx.x;
    if (i < NN) rowptr[i] += bsums[i / SCAN_BLK];
    if (i == 0) rowptr[NN] = NE;
}

// ---------------- generic add-offsets (histm) ----------------
__global__ __launch_bounds__(256) void scan_add_kernel(int* __restrict__ data,
                                                       const int* __restrict__ bsums, int L) {
    int i = blockIdx.x * 256 + threadIdx.x;
    if (i < L) data[i] += bsums[i / SCAN_BLK];
}

// ---------------- radix pass: deterministic coarse scatter via scanned LDS cursors ----------------
// Each (block,bucket) owns a private contiguous run of tmp -> single-XCD lines,
// writeback ~= payload, zero global atomics.
__global__ __launch_bounds__(256) void scatter2_kernel(const int* __restrict__ src,
                                                       const int* __restrict__ dst,
                                                       const int* __restrict__ histm,
                                                       int* __restrict__ tmp) {
    __shared__ int lcur[256];
    int blk = blockIdx.x, tid = threadIdx.x;
    if (tid < NBUCK2) lcur[tid] = histm[tid * NCHK + blk];
    __syncthreads();
    int base = blk * CHUNK;
#pragma unroll
    for (int t = 0; t < CHUNK / 256; t++) {
        int e = base + t * 256 + tid;
        if (e < NE) {
            int d = dst[e];
            int p = atomicAdd(&lcur[d >> BSH], 1);      // LDS atomic
            tmp[p] = src[e] | ((d & 511) << 17);        // src<2^17, 9-bit local dst
        }
    }
}

// ---------------- fine placement: one block per bucket, LDS cursors ----------------
__global__ __launch_bounds__(256) void place_kernel(const int* __restrict__ rowptr,
                                                    const int* __restrict__ tmp,
                                                    int* __restrict__ esrc) {
    __shared__ int lcur[512];
    int b = blockIdx.x, tid = threadIdx.x;
    int lo = b << BSH;
    int hi = lo + 512; if (hi > NN) hi = NN;
    for (int t = tid; t < 512; t += 256) {
        int node = lo + t;
        lcur[t] = (node < NN) ? rowptr[node] : NE;
    }
    __syncthreads();
    int beg = rowptr[lo], end = rowptr[hi];
    for (int e = beg + tid; e < end; e += 256) {
        int v = tmp[e];
        int p = atomicAdd(&lcur[v >> 17], 1);           // LDS atomic
        esrc[p] = v & 0x1FFFF;
    }
}

// ---------------- gather-aggregate: one wave per node, mean fused ----------------
template <int K>
__global__ __launch_bounds__(256) void aggregate_kernel(const float* __restrict__ feat,
                                                        const int* __restrict__ rowptr,
                                                        const int* __restrict__ esrc,
                                                        float* __restrict__ agg) {
    int node = blockIdx.x * 4 + (threadIdx.x >> 6);
    int lane = threadIdx.x & 63;
    if (node >= NN) return;
    int beg = rowptr[node], end = rowptr[node + 1];

    float acc0 = 0.0f, acc1 = 0.0f;
    int e = beg;
    for (; e + 3 < end; e += 4) {                       // 4 edges in flight
        int s0 = esrc[e], s1 = esrc[e + 1], s2 = esrc[e + 2], s3 = esrc[e + 3];
        acc0 += feat[s0 * K + lane];
        acc0 += feat[s1 * K + lane];
        acc0 += feat[s2 * K + lane];
        acc0 += feat[s3 * K + lane];
        if (K == 128) {
            acc1 += feat[s0 * K + 64 + lane];
            acc1 += feat[s1 * K + 64 + lane];
            acc1 += feat[s2 * K + 64 + lane];
            acc1 += feat[s3 * K + 64 + lane];
        }
    }
    for (; e < end; e++) {
        int s = esrc[e];
        acc0 += feat[s * K + lane];
        if (K == 128) acc1 += feat[s * K + 64 + lane];
    }
    float inv = 1.0f / fmaxf((float)(end - beg), 1.0f);
    agg[node * K + lane] = acc0 * inv;
    if (K == 128) agg[node * K + 64 + lane] = acc1 * inv;
}

// ---------------- fused dual-input tiled GEMM ----------------
// out[n, 0:128] = A1[n,0:KA] @ Wa.T + A2[n,0:KB] @ Wb.T + bias   (+ReLU)
// A2/out deliberately NOT __restrict__: layer 2 is in-place on d_out.
template <int KA, int KB, bool RELU>
__global__ __launch_bounds__(256, 4) void gemm_kernel(const float* __restrict__ A1,
                                                      const float* A2,
                                                      const float* __restrict__ Wa,
                                                      const float* __restrict__ Wb,
                                                      const float* __restrict__ bias,
                                                      float* out) {
    __shared__ float As[32][128];
    __shared__ float Bs[32][128];

    const int t = threadIdx.x;
    const int base = blockIdx.x * 128;
    const int half = t & 1;
    const int srow = t >> 1;
    const int ni = t & 15;
    const int ji = t >> 4;

    float acc[8][8];
#pragma unroll
    for (int i = 0; i < 8; i++)
#pragma unroll
        for (int j = 0; j < 8; j++) acc[i][j] = 0.0f;

    const int NCH = (KA + KB) / 32;
#pragma unroll
    for (int c = 0; c < NCH; ++c) {
        const bool inA = (c * 32) < KA;
        const float* Ap = inA ? A1 : A2;
        const float* Wp = inA ? Wa : Wb;
        const int K  = inA ? KA : KB;
        const int kb = inA ? c * 32 : c * 32 - KA;

        __syncthreads();
        {
            int gn = base + srow;
            if (gn > NN - 1) gn = NN - 1;               // clamp: tail rows discarded later
            const float* ar = Ap + (size_t)gn * K + kb + half * 16;
            const float* wr = Wp + (size_t)srow * K + kb + half * 16;
#pragma unroll
            for (int u = 0; u < 4; ++u) {
                float4 av = *(const float4*)(ar + u * 4);
                float4 wv = *(const float4*)(wr + u * 4);
                int k0 = half * 16 + u * 4;
                As[k0 + 0][srow] = av.x; As[k0 + 1][srow] = av.y;
                As[k0 + 2][srow] = av.z; As[k0 + 3][srow] = av.w;
                Bs[k0 + 0][srow] = wv.x; Bs[k0 + 1][srow] = wv.y;
                Bs[k0 + 2][srow] = wv.z; Bs[k0 + 3][srow] = wv.w;
            }
        }
        __syncthreads();

#pragma unroll 4
        for (int k = 0; k < 32; ++k) {
            float4 a0 = *(const float4*)&As[k][ni * 4];
            float4 a1 = *(const float4*)&As[k][64 + ni * 4];
            float4 b0 = *(const float4*)&Bs[k][ji * 4];
            float4 b1 = *(const float4*)&Bs[k][64 + ji * 4];
            float a[8] = {a0.x, a0.y, a0.z, a0.w, a1.x, a1.y, a1.z, a1.w};
            float b[8] = {b0.x, b0.y, b0.z, b0.w, b1.x, b1.y, b1.z, b1.w};
#pragma unroll
            for (int i = 0; i < 8; ++i)
#pragma unroll
                for (int j = 0; j < 8; ++j) acc[i][j] += a[i] * b[j];
        }
    }

    float4 bz0 = *(const float4*)(bias + ji * 4);
    float4 bz1 = *(const float4*)(bias + 64 + ji * 4);
#pragma unroll
    for (int i = 0; i < 8; ++i) {
        int r = base + (i < 4 ? ni * 4 + i : 64 + ni * 4 + (i - 4));
        if (r >= NN) continue;
        float4 o0, o1;
        o0.x = acc[i][0] + bz0.x; o0.y = acc[i][1] + bz0.y;
        o0.z = acc[i][2] + bz0.z; o0.w = acc[i][3] + bz0.w;
        o1.x = acc[i][4] + bz1.x; o1.y = acc[i][5] + bz1.y;
        o1.z = acc[i][6] + bz1.z; o1.w = acc[i][7] + bz1.w;
        if (RELU) {
            o0.x = fmaxf(o0.x, 0.0f); o0.y = fmaxf(o0.y, 0.0f);
            o0.z = fmaxf(o0.z, 0.0f); o0.w = fmaxf(o0.w, 0.0f);
            o1.x = fmaxf(o1.x, 0.0f); o1.y = fmaxf(o1.y, 0.0f);
            o1.z = fmaxf(o1.z, 0.0f); o1.w = fmaxf(o1.w, 0.0f);
        }
        float* op = out + (size_t)r * 128;
        *(float4*)(op + ji * 4) = o0;
        *(float4*)(op + 64 + ji * 4) = o1;
    }
}

extern "C" void kernel_launch(void* const* d_in, const int* in_sizes, int n_in,
                              void* d_out, int out_size, void* d_ws, size_t ws_size,
                              hipStream_t stream) {
    const float* x   = (const float*)d_in[0];
    const int*   ei  = (const int*)d_in[1];
    const float* W1l = (const float*)d_in[2];
    const float* W1r = (const float*)d_in[3];
    const float* b1  = (const float*)d_in[4];
    const float* W2l = (const float*)d_in[5];
    const float* W2r = (const float*)d_in[6];
    const float* b2  = (const float*)d_in[7];
    float* out = (float*)d_out;

    const int* src = ei;        // edge_index[0]
    const int* dst = ei + NE;   // edge_index[1]

    // workspace layout
    char* ws = (char*)d_ws;
    int*   rowptr = (int*)ws;                        // (NN+1) ints      [0, 401408)
    int*   esrc   = (int*)(ws + 401408);             // NE ints          [401408, 6801408)
    float* agg    = (float*)(ws + 6803456);          // NN*128 floats    [6803456, +51.2MB)
    // transients aliasing the agg region (all dead before agg is written):
    int* histm = (int*)(ws + 6803456);               // L2T ints (~154 KB), lower half
    int* bsums = (int*)(ws + 6803456 + 262144);      // <=64 ints, lower half
    int* tmp   = (int*)(ws + 6803456 + 26214400);    // NE ints, upper half (first write
                                                     // to upper half is aggregate<128>)
    const int NB  = (NN + 255) / 256;
    const int NBT = (NN + 127) / 128;                // gemm tiles
    const int NSB2 = (L2T + SCAN_BLK - 1) / SCAN_BLK;  // 19

    // ---- build CSR (edge list sorted by dst), shared by both layers ----
    hipMemsetAsync(rowptr, 0, 401408, stream);
    hist_kernel<<<(NE + 255) / 256, 256, 0, stream>>>(dst, rowptr);
    hist2_kernel<<<NCHK, 256, 0, stream>>>(dst, histm);
    // scan rowptr
    scan1_kernel<<<NSB, 256, 0, stream>>>(rowptr, bsums, NN);
    scan2_kernel<<<1, 64, 0, stream>>>(bsums, NSB);
    scan3_kernel<<<NB, 256, 0, stream>>>(rowptr, bsums);
    // scan histm (bucket-major)
    scan1_kernel<<<NSB2, 256, 0, stream>>>(histm, bsums, L2T);
    scan2_kernel<<<1, 64, 0, stream>>>(bsums, NSB2);
    scan_add_kernel<<<(L2T + 255) / 256, 256, 0, stream>>>(histm, bsums, L2T);
    // deterministic partition + fine placement
    scatter2_kernel<<<NCHK, 256, 0, stream>>>(src, dst, histm, tmp);
    place_kernel<<<NBUCK2, 256, 0, stream>>>(rowptr, tmp, esrc);

    // ---- layer 1: out = relu(mean(agg) @ W1l.T + x @ W1r.T + b1) ----
    aggregate_kernel<64><<<NN / 4, 256, 0, stream>>>(x, rowptr, esrc, agg);
    gemm_kernel<64, 64, true><<<NBT, 256, 0, stream>>>(agg, x, W1l, W1r, b1, out);

    // ---- layer 2: out = mean(agg2) @ W2l.T + h @ W2r.T + b2  (h = out, in-place) ----
    aggregate_kernel<128><<<NN / 4, 256, 0, stream>>>(out, rowptr, esrc, agg);
    gemm_kernel<128, 128, false><<<NBT, 256, 0, stream>>>(agg, out, W2l, W2r, b2, out);
}

// Round 7
// 488.380 us; speedup vs baseline: 1.4903x; 1.0921x over previous
//
#include <hip/hip_runtime.h>

#define NN 100000
#define NE 1600000
#define SCAN_BLK 2048
#define NSB ((NN + SCAN_BLK - 1) / SCAN_BLK)   // 49 blocks for rowptr scan

#define BSH 9                                  // 512 nodes/bucket
#define NBUCK2 ((NN + 511) / 512)              // 196 coarse buckets
#define CHUNK 8192                             // edges per partition block
#define NCHK ((NE + CHUNK - 1) / CHUNK)        // 196 chunks
#define L2T (NBUCK2 * NCHK)                    // 38416

// ---- bf16 helpers (RNE) ----
__device__ __forceinline__ unsigned short f2bf(float f) {
    unsigned u = __float_as_uint(f);
    u += 0x7FFFu + ((u >> 16) & 1u);
    return (unsigned short)(u >> 16);
}
__device__ __forceinline__ float bf2f(unsigned short h) {
    return __uint_as_float(((unsigned)h) << 16);
}

// ---------------- int degree histogram ----------------
__global__ __launch_bounds__(256) void hist_kernel(const int* __restrict__ dst,
                                                   int* __restrict__ hist) {
    int e = blockIdx.x * 256 + threadIdx.x;
    if (e < NE) atomicAdd(&hist[dst[e]], 1);
}

// ---------------- per-chunk bucket histogram (LDS only) ----------------
__global__ __launch_bounds__(256) void hist2_kernel(const int* __restrict__ dst,
                                                    int* __restrict__ histm) {
    __shared__ int lh[256];
    int blk = blockIdx.x, tid = threadIdx.x;
    lh[tid] = 0;
    __syncthreads();
    int base = blk * CHUNK;
#pragma unroll
    for (int t = 0; t < CHUNK / 256; t++) {
        int e = base + t * 256 + tid;
        if (e < NE) atomicAdd(&lh[dst[e] >> BSH], 1);
    }
    __syncthreads();
    if (tid < NBUCK2) histm[tid * NCHK + blk] = lh[tid];   // bucket-major
}

// ---------------- exclusive scan, stage 1 ----------------
__global__ __launch_bounds__(256) void scan1_kernel(int* __restrict__ data,
                                                    int* __restrict__ bsums, int L) {
    __shared__ int s[256];
    int bid = blockIdx.x, tid = threadIdx.x;
    int base = bid * SCAN_BLK + tid * 8;
    int v[8];
    int sum = 0;
#pragma unroll
    for (int t = 0; t < 8; t++) {
        int idx = base + t;
        v[t] = (idx < L) ? data[idx] : 0;
        sum += v[t];
    }
    s[tid] = sum;
    __syncthreads();
    for (int off = 1; off < 256; off <<= 1) {
        int val = (tid >= off) ? s[tid - off] : 0;
        __syncthreads();
        s[tid] += val;
        __syncthreads();
    }
    int excl = s[tid] - sum;
    if (tid == 255) bsums[bid] = s[255];
    int run = excl;
#pragma unroll
    for (int t = 0; t < 8; t++) {
        int idx = base + t;
        if (idx < L) data[idx] = run;
        run += v[t];
    }
}

// ---------------- scan stage 2: one wave over n<=64 sums ----------------
__global__ __launch_bounds__(64) void scan2_kernel(int* __restrict__ bsums, int n) {
    int tid = threadIdx.x;
    int orig = (tid < n) ? bsums[tid] : 0;
    int v = orig;
    for (int off = 1; off < 64; off <<= 1) {
        int nb = __shfl_up(v, off, 64);
        if (tid >= off) v += nb;
    }
    if (tid < n) bsums[tid] = v - orig;
}

// ---------------- scan stage 3 (rowptr) ----------------
__global__ __launch_bounds__(256) void scan3_kernel(int* __restrict__ rowptr,
                                                    const int* __restrict__ bsums) {
    int i = blockIdx.x * 256 + threadIdx.x;
    if (i < NN) rowptr[i] += bsums[i / SCAN_BLK];
    if (i == 0) rowptr[NN] = NE;
}

// ---------------- add offsets (histm) ----------------
__global__ __launch_bounds__(256) void scan_add_kernel(int* __restrict__ data,
                                                       const int* __restrict__ bsums, int L) {
    int i = blockIdx.x * 256 + threadIdx.x;
    if (i < L) data[i] += bsums[i / SCAN_BLK];
}

// ---------------- deterministic coarse scatter (LDS cursors) ----------------
__global__ __launch_bounds__(256) void scatter2_kernel(const int* __restrict__ src,
                                                       const int* __restrict__ dst,
                                                       const int* __restrict__ histm,
                                                       int* __restrict__ tmp) {
    __shared__ int lcur[256];
    int blk = blockIdx.x, tid = threadIdx.x;
    if (tid < NBUCK2) lcur[tid] = histm[tid * NCHK + blk];
    __syncthreads();
    int base = blk * CHUNK;
#pragma unroll
    for (int t = 0; t < CHUNK / 256; t++) {
        int e = base + t * 256 + tid;
        if (e < NE) {
            int d = dst[e];
            int p = atomicAdd(&lcur[d >> BSH], 1);      // LDS atomic
            tmp[p] = src[e] | ((d & 511) << 17);        // src<2^17
        }
    }
}

// ---------------- fine placement (LDS cursors) ----------------
__global__ __launch_bounds__(256) void place_kernel(const int* __restrict__ rowptr,
                                                    const int* __restrict__ tmp,
                                                    int* __restrict__ esrc) {
    __shared__ int lcur[512];
    int b = blockIdx.x, tid = threadIdx.x;
    int lo = b << BSH;
    int hi = lo + 512; if (hi > NN) hi = NN;
    for (int t = tid; t < 512; t += 256) {
        int node = lo + t;
        lcur[t] = (node < NN) ? rowptr[node] : NE;
    }
    __syncthreads();
    int beg = rowptr[lo], end = rowptr[hi];
    for (int e = beg + tid; e < end; e += 256) {
        int v = tmp[e];
        int p = atomicAdd(&lcur[v >> 17], 1);           // LDS atomic
        esrc[p] = v & 0x1FFFF;
    }
}

// ---------------- fp32 -> bf16 convert (x) ----------------
__global__ __launch_bounds__(256) void cvt_kernel(const float* __restrict__ in,
                                                  unsigned short* __restrict__ out, int n4) {
    int i = blockIdx.x * 256 + threadIdx.x;
    if (i < n4) {
        float4 f = ((const float4*)in)[i];
        ((ushort4*)out)[i] = make_ushort4(f2bf(f.x), f2bf(f.y), f2bf(f.z), f2bf(f.w));
    }
}

// ---------------- bf16 mean-aggregate, K=64: wave/node, 2 edges per iter ----------------
__global__ __launch_bounds__(256) void agg64_kernel(const unsigned short* __restrict__ feat,
                                                    const int* __restrict__ rowptr,
                                                    const int* __restrict__ esrc,
                                                    unsigned short* __restrict__ agg) {
    int node = blockIdx.x * 4 + (threadIdx.x >> 6);
    int lane = threadIdx.x & 63;
    int half = lane >> 5;          // which edge of the pair
    int fi = (lane & 31) * 2;      // feature pair index
    int beg = rowptr[node], end = rowptr[node + 1];

    float ax = 0.0f, ay = 0.0f;
    int e = beg;
    for (; e + 3 < end; e += 4) {
        int sA = esrc[e + half];
        int sB = esrc[e + 2 + half];
        ushort2 uA = *(const ushort2*)(feat + (size_t)sA * 64 + fi);
        ushort2 uB = *(const ushort2*)(feat + (size_t)sB * 64 + fi);
        ax += bf2f(uA.x) + bf2f(uB.x);
        ay += bf2f(uA.y) + bf2f(uB.y);
    }
    for (; e + 1 < end; e += 2) {
        int s = esrc[e + half];
        ushort2 u = *(const ushort2*)(feat + (size_t)s * 64 + fi);
        ax += bf2f(u.x); ay += bf2f(u.y);
    }
    if (e < end && half == 0) {
        int s = esrc[e];
        ushort2 u = *(const ushort2*)(feat + (size_t)s * 64 + fi);
        ax += bf2f(u.x); ay += bf2f(u.y);
    }
    ax += __shfl_down(ax, 32);
    ay += __shfl_down(ay, 32);
    if (half == 0) {
        float inv = 1.0f / fmaxf((float)(end - beg), 1.0f);
        *(ushort2*)(agg + (size_t)node * 64 + fi) =
            make_ushort2(f2bf(ax * inv), f2bf(ay * inv));
    }
}

// ---------------- bf16 mean-aggregate, K=128: wave/node, full row per load ----------------
__global__ __launch_bounds__(256) void agg128_kernel(const unsigned short* __restrict__ feat,
                                                     const int* __restrict__ rowptr,
                                                     const int* __restrict__ esrc,
                                                     unsigned short* __restrict__ agg) {
    int node = blockIdx.x * 4 + (threadIdx.x >> 6);
    int lane = threadIdx.x & 63;
    int beg = rowptr[node], end = rowptr[node + 1];

    float ax = 0.0f, ay = 0.0f;
    int e = beg;
    for (; e + 3 < end; e += 4) {
        int s0 = esrc[e], s1 = esrc[e + 1], s2 = esrc[e + 2], s3 = esrc[e + 3];
        ushort2 u0 = *(const ushort2*)(feat + (size_t)s0 * 128 + lane * 2);
        ushort2 u1 = *(const ushort2*)(feat + (size_t)s1 * 128 + lane * 2);
        ushort2 u2 = *(const ushort2*)(feat + (size_t)s2 * 128 + lane * 2);
        ushort2 u3 = *(const ushort2*)(feat + (size_t)s3 * 128 + lane * 2);
        ax += bf2f(u0.x) + bf2f(u1.x) + bf2f(u2.x) + bf2f(u3.x);
        ay += bf2f(u0.y) + bf2f(u1.y) + bf2f(u2.y) + bf2f(u3.y);
    }
    for (; e < end; e++) {
        int s = esrc[e];
        ushort2 u = *(const ushort2*)(feat + (size_t)s * 128 + lane * 2);
        ax += bf2f(u.x); ay += bf2f(u.y);
    }
    float inv = 1.0f / fmaxf((float)(end - beg), 1.0f);
    *(ushort2*)(agg + (size_t)node * 128 + lane * 2) =
        make_ushort2(f2bf(ax * inv), f2bf(ay * inv));
}

// ---------------- 16-element row loaders (fp32 / bf16 -> fp32) ----------------
__device__ __forceinline__ void load16(const float* p, float* v) {
#pragma unroll
    for (int u = 0; u < 4; ++u) {
        float4 t = ((const float4*)p)[u];
        v[4 * u + 0] = t.x; v[4 * u + 1] = t.y;
        v[4 * u + 2] = t.z; v[4 * u + 3] = t.w;
    }
}
__device__ __forceinline__ void load16(const unsigned short* p, float* v) {
#pragma unroll
    for (int u = 0; u < 4; ++u) {
        ushort4 t = ((const ushort4*)p)[u];
        v[4 * u + 0] = bf2f(t.x); v[4 * u + 1] = bf2f(t.y);
        v[4 * u + 2] = bf2f(t.z); v[4 * u + 3] = bf2f(t.w);
    }
}

// ---------------- fused dual-input tiled GEMM (mixed dtypes) ----------------
// out[n,0:128] = A1[n,0:KA] @ Wa.T + A2[n,0:KB] @ Wb.T + bias  (+ReLU, opt bf16 out)
template <int KA, int KB, bool RELU, bool OUTBF, typename TA1, typename TA2>
__global__ __launch_bounds__(256, 4) void gemm_kernel(const TA1* __restrict__ A1,
                                                      const TA2* __restrict__ A2,
                                                      const float* __restrict__ Wa,
                                                      const float* __restrict__ Wb,
                                                      const float* __restrict__ bias,
                                                      void* __restrict__ outv) {
    __shared__ float As[32][128];
    __shared__ float Bs[32][128];

    const int t = threadIdx.x;
    const int base = blockIdx.x * 128;
    const int half = t & 1;
    const int srow = t >> 1;
    const int ni = t & 15;
    const int ji = t >> 4;

    float acc[8][8];
#pragma unroll
    for (int i = 0; i < 8; i++)
#pragma unroll
        for (int j = 0; j < 8; j++) acc[i][j] = 0.0f;

    const int NCH = (KA + KB) / 32;
#pragma unroll
    for (int c = 0; c < NCH; ++c) {
        const bool inA = (c * 32) < KA;
        __syncthreads();
        {
            int gn = base + srow;
            if (gn > NN - 1) gn = NN - 1;               // clamp: tail discarded in epilogue
            float av[16], wv[16];
            if (inA) {
                int kb = c * 32;
                load16(A1 + (size_t)gn * KA + kb + half * 16, av);
                load16(Wa + (size_t)srow * KA + kb + half * 16, wv);
            } else {
                int kb = c * 32 - KA;
                load16(A2 + (size_t)gn * KB + kb + half * 16, av);
                load16(Wb + (size_t)srow * KB + kb + half * 16, wv);
            }
#pragma unroll
            for (int u = 0; u < 16; ++u) {
                int k0 = half * 16 + u;
                As[k0][srow] = av[u];
                Bs[k0][srow] = wv[u];
            }
        }
        __syncthreads();

#pragma unroll 4
        for (int k = 0; k < 32; ++k) {
            float4 a0 = *(const float4*)&As[k][ni * 4];
            float4 a1 = *(const float4*)&As[k][64 + ni * 4];
            float4 b0 = *(const float4*)&Bs[k][ji * 4];
            float4 b1 = *(const float4*)&Bs[k][64 + ji * 4];
            float a[8] = {a0.x, a0.y, a0.z, a0.w, a1.x, a1.y, a1.z, a1.w};
            float b[8] = {b0.x, b0.y, b0.z, b0.w, b1.x, b1.y, b1.z, b1.w};
#pragma unroll
            for (int i = 0; i < 8; ++i)
#pragma unroll
                for (int j = 0; j < 8; ++j) acc[i][j] += a[i] * b[j];
        }
    }

    float4 bz0 = *(const float4*)(bias + ji * 4);
    float4 bz1 = *(const float4*)(bias + 64 + ji * 4);
#pragma unroll
    for (int i = 0; i < 8; ++i) {
        int r = base + (i < 4 ? ni * 4 + i : 64 + ni * 4 + (i - 4));
        if (r >= NN) continue;
        float o[8];
        o[0] = acc[i][0] + bz0.x; o[1] = acc[i][1] + bz0.y;
        o[2] = acc[i][2] + bz0.z; o[3] = acc[i][3] + bz0.w;
        o[4] = acc[i][4] + bz1.x; o[5] = acc[i][5] + bz1.y;
        o[6] = acc[i][6] + bz1.z; o[7] = acc[i][7] + bz1.w;
        if (RELU) {
#pragma unroll
            for (int u = 0; u < 8; ++u) o[u] = fmaxf(o[u], 0.0f);
        }
        if (OUTBF) {
            unsigned short* ob = (unsigned short*)outv + (size_t)r * 128;
            *(ushort4*)(ob + ji * 4) =
                make_ushort4(f2bf(o[0]), f2bf(o[1]), f2bf(o[2]), f2bf(o[3]));
            *(ushort4*)(ob + 64 + ji * 4) =
                make_ushort4(f2bf(o[4]), f2bf(o[5]), f2bf(o[6]), f2bf(o[7]));
        } else {
            float* op = (float*)outv + (size_t)r * 128;
            *(float4*)(op + ji * 4)      = make_float4(o[0], o[1], o[2], o[3]);
            *(float4*)(op + 64 + ji * 4) = make_float4(o[4], o[5], o[6], o[7]);
        }
    }
}

extern "C" void kernel_launch(void* const* d_in, const int* in_sizes, int n_in,
                              void* d_out, int out_size, void* d_ws, size_t ws_size,
                              hipStream_t stream) {
    const float* x   = (const float*)d_in[0];
    const int*   ei  = (const int*)d_in[1];
    const float* W1l = (const float*)d_in[2];
    const float* W1r = (const float*)d_in[3];
    const float* b1  = (const float*)d_in[4];
    const float* W2l = (const float*)d_in[5];
    const float* W2r = (const float*)d_in[6];
    const float* b2  = (const float*)d_in[7];
    float* out = (float*)d_out;

    const int* src = ei;        // edge_index[0]
    const int* dst = ei + NE;   // edge_index[1]

    // ---- workspace layout (total 58,003,456 B — proven available) ----
    char* ws = (char*)d_ws;
    int* rowptr = (int*)ws;                              // [0, 401408)
    int* esrc   = (int*)(ws + 401408);                   // NE ints, ends 6801408
    unsigned short* aggB = (unsigned short*)(ws + 6803456);  // NN*128 bf16 (25.6 MB)
    char* E = ws + 32403456;                             // 25.6 MB multi-use region
    unsigned short* hb = (unsigned short*)E;             // NN*128 bf16 (gemm1 -> gemm2)
    // transients inside E, all dead before gemm1 writes hb:
    int* tmp   = (int*)E;                                // NE ints   [E, E+6.4M)
    int* histm = (int*)(E + 6400000);                    // L2T ints
    int* bsums = (int*)(E + 6560000);                    // <=64 ints
    unsigned short* xb = (unsigned short*)(E + 6563840); // NN*64 bf16 (12.8 MB)

    const int NB  = (NN + 255) / 256;
    const int NBT = (NN + 127) / 128;
    const int NSB2 = (L2T + SCAN_BLK - 1) / SCAN_BLK;    // 19

    // ---- build CSR (edge list sorted by dst) ----
    hipMemsetAsync(rowptr, 0, 401408, stream);
    hist_kernel<<<(NE + 255) / 256, 256, 0, stream>>>(dst, rowptr);
    hist2_kernel<<<NCHK, 256, 0, stream>>>(dst, histm);
    scan1_kernel<<<NSB, 256, 0, stream>>>(rowptr, bsums, NN);
    scan2_kernel<<<1, 64, 0, stream>>>(bsums, NSB);
    scan3_kernel<<<NB, 256, 0, stream>>>(rowptr, bsums);
    scan1_kernel<<<NSB2, 256, 0, stream>>>(histm, bsums, L2T);
    scan2_kernel<<<1, 64, 0, stream>>>(bsums, NSB2);
    scan_add_kernel<<<(L2T + 255) / 256, 256, 0, stream>>>(histm, bsums, L2T);
    scatter2_kernel<<<NCHK, 256, 0, stream>>>(src, dst, histm, tmp);
    place_kernel<<<NBUCK2, 256, 0, stream>>>(rowptr, tmp, esrc);

    // ---- bf16 feature plane for gathers ----
    cvt_kernel<<<(NN * 64 / 4 + 255) / 256, 256, 0, stream>>>(x, xb, NN * 64 / 4);

    // ---- layer 1: hb = bf16(relu(mean(agg) @ W1l.T + x @ W1r.T + b1)) ----
    agg64_kernel<<<NN / 4, 256, 0, stream>>>(xb, rowptr, esrc, aggB);
    gemm_kernel<64, 64, true, true, unsigned short, float>
        <<<NBT, 256, 0, stream>>>(aggB, x, W1l, W1r, b1, hb);

    // ---- layer 2: out = mean(agg2) @ W2l.T + hb @ W2r.T + b2 ----
    agg128_kernel<<<NN / 4, 256, 0, stream>>>(hb, rowptr, esrc, aggB);
    gemm_kernel<128, 128, false, false, unsigned short, unsigned short>
        <<<NBT, 256, 0, stream>>>(aggB, hb, W2l, W2r, b2, out);
}

// Round 8
// 423.677 us; speedup vs baseline: 1.7179x; 1.1527x over previous
//
#include <hip/hip_runtime.h>

#define NN 100000
#define NE 1600000
#define SCAN_BLK 2048
#define NSB ((NN + SCAN_BLK - 1) / SCAN_BLK)   // 49 blocks for rowptr scan

#define BSH 9                                  // 512 nodes/bucket
#define NBUCK2 ((NN + 511) / 512)              // 196 coarse buckets
#define CHUNK 8192                             // edges per partition block
#define NCHK ((NE + CHUNK - 1) / CHUNK)        // 196 chunks
#define L2T (NBUCK2 * NCHK)                    // 38416
#define NSTRIP (NN / 32)                       // 3125 exact

using bf16x8 = __attribute__((ext_vector_type(8))) short;
using f32x16 = __attribute__((ext_vector_type(16))) float;

// ---- bf16 helpers (RNE) ----
__device__ __forceinline__ unsigned short f2bf(float f) {
    unsigned u = __float_as_uint(f);
    u += 0x7FFFu + ((u >> 16) & 1u);
    return (unsigned short)(u >> 16);
}
__device__ __forceinline__ float bf2f(unsigned short h) {
    return __uint_as_float(((unsigned)h) << 16);
}

// ---------------- int degree histogram ----------------
__global__ __launch_bounds__(256) void hist_kernel(const int* __restrict__ dst,
                                                   int* __restrict__ hist) {
    int e = blockIdx.x * 256 + threadIdx.x;
    if (e < NE) atomicAdd(&hist[dst[e]], 1);
}

// ---------------- per-chunk bucket histogram (LDS only) ----------------
__global__ __launch_bounds__(256) void hist2_kernel(const int* __restrict__ dst,
                                                    int* __restrict__ histm) {
    __shared__ int lh[256];
    int blk = blockIdx.x, tid = threadIdx.x;
    lh[tid] = 0;
    __syncthreads();
    int base = blk * CHUNK;
#pragma unroll
    for (int t = 0; t < CHUNK / 256; t++) {
        int e = base + t * 256 + tid;
        if (e < NE) atomicAdd(&lh[dst[e] >> BSH], 1);
    }
    __syncthreads();
    if (tid < NBUCK2) histm[tid * NCHK + blk] = lh[tid];   // bucket-major
}

// ---------------- exclusive scan, stage 1 ----------------
__global__ __launch_bounds__(256) void scan1_kernel(int* __restrict__ data,
                                                    int* __restrict__ bsums, int L) {
    __shared__ int s[256];
    int bid = blockIdx.x, tid = threadIdx.x;
    int base = bid * SCAN_BLK + tid * 8;
    int v[8];
    int sum = 0;
#pragma unroll
    for (int t = 0; t < 8; t++) {
        int idx = base + t;
        v[t] = (idx < L) ? data[idx] : 0;
        sum += v[t];
    }
    s[tid] = sum;
    __syncthreads();
    for (int off = 1; off < 256; off <<= 1) {
        int val = (tid >= off) ? s[tid - off] : 0;
        __syncthreads();
        s[tid] += val;
        __syncthreads();
    }
    int excl = s[tid] - sum;
    if (tid == 255) bsums[bid] = s[255];
    int run = excl;
#pragma unroll
    for (int t = 0; t < 8; t++) {
        int idx = base + t;
        if (idx < L) data[idx] = run;
        run += v[t];
    }
}

// ---------------- scan stage 2: one wave over n<=64 sums ----------------
__global__ __launch_bounds__(64) void scan2_kernel(int* __restrict__ bsums, int n) {
    int tid = threadIdx.x;
    int orig = (tid < n) ? bsums[tid] : 0;
    int v = orig;
    for (int off = 1; off < 64; off <<= 1) {
        int nb = __shfl_up(v, off, 64);
        if (tid >= off) v += nb;
    }
    if (tid < n) bsums[tid] = v - orig;
}

// ---------------- scan stage 3 (rowptr) ----------------
__global__ __launch_bounds__(256) void scan3_kernel(int* __restrict__ rowptr,
                                                    const int* __restrict__ bsums) {
    int i = blockIdx.x * 256 + threadIdx.x;
    if (i < NN) rowptr[i] += bsums[i / SCAN_BLK];
    if (i == 0) rowptr[NN] = NE;
}

// ---------------- add offsets (histm) ----------------
__global__ __launch_bounds__(256) void scan_add_kernel(int* __restrict__ data,
                                                       const int* __restrict__ bsums, int L) {
    int i = blockIdx.x * 256 + threadIdx.x;
    if (i < L) data[i] += bsums[i / SCAN_BLK];
}

// ---------------- deterministic coarse scatter (LDS cursors) ----------------
__global__ __launch_bounds__(256) void scatter2_kernel(const int* __restrict__ src,
                                                       const int* __restrict__ dst,
                                                       const int* __restrict__ histm,
                                                       int* __restrict__ tmp) {
    __shared__ int lcur[256];
    int blk = blockIdx.x, tid = threadIdx.x;
    if (tid < NBUCK2) lcur[tid] = histm[tid * NCHK + blk];
    __syncthreads();
    int base = blk * CHUNK;
#pragma unroll
    for (int t = 0; t < CHUNK / 256; t++) {
        int e = base + t * 256 + tid;
        if (e < NE) {
            int d = dst[e];
            int p = atomicAdd(&lcur[d >> BSH], 1);      // LDS atomic
            tmp[p] = src[e] | ((d & 511) << 17);        // src<2^17
        }
    }
}

// ---------------- fine placement (LDS cursors) ----------------
__global__ __launch_bounds__(256) void place_kernel(const int* __restrict__ rowptr,
                                                    const int* __restrict__ tmp,
                                                    int* __restrict__ esrc) {
    __shared__ int lcur[512];
    int b = blockIdx.x, tid = threadIdx.x;
    int lo = b << BSH;
    int hi = lo + 512; if (hi > NN) hi = NN;
    for (int t = tid; t < 512; t += 256) {
        int node = lo + t;
        lcur[t] = (node < NN) ? rowptr[node] : NE;
    }
    __syncthreads();
    int beg = rowptr[lo], end = rowptr[hi];
    for (int e = beg + tid; e < end; e += 256) {
        int v = tmp[e];
        int p = atomicAdd(&lcur[v >> 17], 1);           // LDS atomic
        esrc[p] = v & 0x1FFFF;
    }
}

// ---------------- fp32 -> bf16 convert ----------------
__global__ __launch_bounds__(256) void cvt_kernel(const float* __restrict__ in,
                                                  unsigned short* __restrict__ out, int n4) {
    int i = blockIdx.x * 256 + threadIdx.x;
    if (i < n4) {
        float4 f = ((const float4*)in)[i];
        ((ushort4*)out)[i] = make_ushort4(f2bf(f.x), f2bf(f.y), f2bf(f.z), f2bf(f.w));
    }
}

// ---------------- bf16 mean-aggregate, K=64: wave/node, 2 edges per iter ----------------
__global__ __launch_bounds__(256) void agg64_kernel(const unsigned short* __restrict__ feat,
                                                    const int* __restrict__ rowptr,
                                                    const int* __restrict__ esrc,
                                                    unsigned short* __restrict__ agg) {
    int node = blockIdx.x * 4 + (threadIdx.x >> 6);
    int lane = threadIdx.x & 63;
    int half = lane >> 5;          // which edge of the pair
    int fi = (lane & 31) * 2;      // feature pair index
    int beg = rowptr[node], end = rowptr[node + 1];

    float ax = 0.0f, ay = 0.0f;
    int e = beg;
    for (; e + 3 < end; e += 4) {
        int sA = esrc[e + half];
        int sB = esrc[e + 2 + half];
        ushort2 uA = *(const ushort2*)(feat + (size_t)sA * 64 + fi);
        ushort2 uB = *(const ushort2*)(feat + (size_t)sB * 64 + fi);
        ax += bf2f(uA.x) + bf2f(uB.x);
        ay += bf2f(uA.y) + bf2f(uB.y);
    }
    for (; e + 1 < end; e += 2) {
        int s = esrc[e + half];
        ushort2 u = *(const ushort2*)(feat + (size_t)s * 64 + fi);
        ax += bf2f(u.x); ay += bf2f(u.y);
    }
    if (e < end && half == 0) {
        int s = esrc[e];
        ushort2 u = *(const ushort2*)(feat + (size_t)s * 64 + fi);
        ax += bf2f(u.x); ay += bf2f(u.y);
    }
    ax += __shfl_down(ax, 32);
    ay += __shfl_down(ay, 32);
    if (half == 0) {
        float inv = 1.0f / fmaxf((float)(end - beg), 1.0f);
        *(ushort2*)(agg + (size_t)node * 64 + fi) =
            make_ushort2(f2bf(ax * inv), f2bf(ay * inv));
    }
}

// ---------------- bf16 mean-aggregate, K=128 ----------------
__global__ __launch_bounds__(256) void agg128_kernel(const unsigned short* __restrict__ feat,
                                                     const int* __restrict__ rowptr,
                                                     const int* __restrict__ esrc,
                                                     unsigned short* __restrict__ agg) {
    int node = blockIdx.x * 4 + (threadIdx.x >> 6);
    int lane = threadIdx.x & 63;
    int beg = rowptr[node], end = rowptr[node + 1];

    float ax = 0.0f, ay = 0.0f;
    int e = beg;
    for (; e + 3 < end; e += 4) {
        int s0 = esrc[e], s1 = esrc[e + 1], s2 = esrc[e + 2], s3 = esrc[e + 3];
        ushort2 u0 = *(const ushort2*)(feat + (size_t)s0 * 128 + lane * 2);
        ushort2 u1 = *(const ushort2*)(feat + (size_t)s1 * 128 + lane * 2);
        ushort2 u2 = *(const ushort2*)(feat + (size_t)s2 * 128 + lane * 2);
        ushort2 u3 = *(const ushort2*)(feat + (size_t)s3 * 128 + lane * 2);
        ax += bf2f(u0.x) + bf2f(u1.x) + bf2f(u2.x) + bf2f(u3.x);
        ay += bf2f(u0.y) + bf2f(u1.y) + bf2f(u2.y) + bf2f(u3.y);
    }
    for (; e < end; e++) {
        int s = esrc[e];
        ushort2 u = *(const ushort2*)(feat + (size_t)s * 128 + lane * 2);
        ax += bf2f(u.x); ay += bf2f(u.y);
    }
    float inv = 1.0f / fmaxf((float)(end - beg), 1.0f);
    *(ushort2*)(agg + (size_t)node * 128 + lane * 2) =
        make_ushort2(f2bf(ax * inv), f2bf(ay * inv));
}

// ---------------- MFMA GEMM: out[n,0:128] = A1@Wa.T + A2@Wb.T + bias ----------------
// All operands bf16 row-major; fp32 accumulate in MFMA. One wave = 32-node
// strip x 128 outputs (4 acc tiles of 32x32x16). No LDS: A-frag is 8
// contiguous bf16 of the lane's own row (A[m=lane&31][k=half*8+j]); B-frag is
// 8 contiguous bf16 of W row n=lane&31 — W's natural [out][k] layout. C/D map
// (m74/m101-verified): col=lane&31, row=(reg&3)+8*(reg>>2)+4*half.
template <int K, bool RELU, bool OUTBF>
__global__ __launch_bounds__(256) void gemm_mfma_kernel(
    const unsigned short* __restrict__ A1,
    const unsigned short* __restrict__ A2,
    const unsigned short* __restrict__ Wa,
    const unsigned short* __restrict__ Wb,
    const float* __restrict__ bias,
    void* __restrict__ outv) {
    int strip = blockIdx.x * 4 + (threadIdx.x >> 6);
    if (strip >= NSTRIP) return;
    const int lane = threadIdx.x & 63;
    const int m = lane & 31;
    const int half = lane >> 5;
    const int base = strip * 32;

    f32x16 acc[4];
#pragma unroll
    for (int nb = 0; nb < 4; ++nb)
#pragma unroll
        for (int r = 0; r < 16; ++r) acc[nb][r] = 0.0f;

    const unsigned short* ar1 = A1 + (size_t)(base + m) * K + half * 8;
    const unsigned short* ar2 = A2 + (size_t)(base + m) * K + half * 8;
#pragma unroll
    for (int kc = 0; kc < K; kc += 16) {
        bf16x8 a = *(const bf16x8*)(ar1 + kc);
#pragma unroll
        for (int nb = 0; nb < 4; ++nb) {
            bf16x8 b = *(const bf16x8*)(Wa + (size_t)(nb * 32 + m) * K + kc + half * 8);
            acc[nb] = __builtin_amdgcn_mfma_f32_32x32x16_bf16(a, b, acc[nb], 0, 0, 0);
        }
    }
#pragma unroll
    for (int kc = 0; kc < K; kc += 16) {
        bf16x8 a = *(const bf16x8*)(ar2 + kc);
#pragma unroll
        for (int nb = 0; nb < 4; ++nb) {
            bf16x8 b = *(const bf16x8*)(Wb + (size_t)(nb * 32 + m) * K + kc + half * 8);
            acc[nb] = __builtin_amdgcn_mfma_f32_32x32x16_bf16(a, b, acc[nb], 0, 0, 0);
        }
    }

#pragma unroll
    for (int nb = 0; nb < 4; ++nb) {
        int j = nb * 32 + m;
        float bz = bias[j];
#pragma unroll
        for (int r = 0; r < 16; ++r) {
            int row = (r & 3) + 8 * (r >> 2) + 4 * half;
            float v = acc[nb][r] + bz;
            if (RELU) v = fmaxf(v, 0.0f);
            size_t idx = (size_t)(base + row) * 128 + j;
            if (OUTBF) ((unsigned short*)outv)[idx] = f2bf(v);
            else       ((float*)outv)[idx] = v;
        }
    }
}

extern "C" void kernel_launch(void* const* d_in, const int* in_sizes, int n_in,
                              void* d_out, int out_size, void* d_ws, size_t ws_size,
                              hipStream_t stream) {
    const float* x   = (const float*)d_in[0];
    const int*   ei  = (const int*)d_in[1];
    const float* W1l = (const float*)d_in[2];
    const float* W1r = (const float*)d_in[3];
    const float* b1  = (const float*)d_in[4];
    const float* W2l = (const float*)d_in[5];
    const float* W2r = (const float*)d_in[6];
    const float* b2  = (const float*)d_in[7];
    float* out = (float*)d_out;

    const int* src = ei;        // edge_index[0]
    const int* dst = ei + NE;   // edge_index[1]

    // ---- workspace layout (58,003,456 B total — proven available) ----
    // Lifetimes: rowptr/esrc die after agg128; tmp/histm/bsums die before
    // gemm1 writes hb; xb (aggB upper half) dies before agg128 writes aggB;
    // W1b lives in d_out (untouched until gemm2 epilogue); W2b reuses the
    // rowptr region after agg128.
    char* ws = (char*)d_ws;
    int* rowptr = (int*)ws;                                  // [0, 401408)
    int* esrc   = (int*)(ws + 401408);                       // NE ints
    unsigned short* aggB = (unsigned short*)(ws + 6803456);  // NN*128 bf16 (25.6 MB)
    unsigned short* xb   = aggB + (size_t)NN * 64;           // NN*64 bf16, aggB upper half
    char* E = ws + 32403456;                                 // 25.6 MB region
    unsigned short* hb = (unsigned short*)E;                 // NN*128 bf16
    int* tmp   = (int*)E;                                    // NE ints (transient)
    int* histm = (int*)(E + 6400000);                        // L2T ints (transient)
    int* bsums = (int*)(E + 6560000);                        // <=64 ints (transient)
    // W bf16 copies:
    unsigned short* W1lb = (unsigned short*)d_out;           // 128*64 bf16 (16 KB)
    unsigned short* W1rb = W1lb + 128 * 64;
    unsigned short* W2lb = (unsigned short*)ws;              // 128*128 bf16 (32 KB), after agg128
    unsigned short* W2rb = W2lb + 128 * 128;

    const int NB  = (NN + 255) / 256;
    const int GB  = (NSTRIP + 3) / 4;                        // 782 gemm blocks
    const int NSB2 = (L2T + SCAN_BLK - 1) / SCAN_BLK;        // 19

    // ---- build CSR (edge list sorted by dst) ----
    hipMemsetAsync(rowptr, 0, 401408, stream);
    hist_kernel<<<(NE + 255) / 256, 256, 0, stream>>>(dst, rowptr);
    hist2_kernel<<<NCHK, 256, 0, stream>>>(dst, histm);
    scan1_kernel<<<NSB, 256, 0, stream>>>(rowptr, bsums, NN);
    scan2_kernel<<<1, 64, 0, stream>>>(bsums, NSB);
    scan3_kernel<<<NB, 256, 0, stream>>>(rowptr, bsums);
    scan1_kernel<<<NSB2, 256, 0, stream>>>(histm, bsums, L2T);
    scan2_kernel<<<1, 64, 0, stream>>>(bsums, NSB2);
    scan_add_kernel<<<(L2T + 255) / 256, 256, 0, stream>>>(histm, bsums, L2T);
    scatter2_kernel<<<NCHK, 256, 0, stream>>>(src, dst, histm, tmp);
    place_kernel<<<NBUCK2, 256, 0, stream>>>(rowptr, tmp, esrc);

    // ---- bf16 planes ----
    cvt_kernel<<<(NN * 64 / 4 + 255) / 256, 256, 0, stream>>>(x, xb, NN * 64 / 4);
    cvt_kernel<<<(128 * 64 / 4 + 255) / 256, 256, 0, stream>>>(W1l, W1lb, 128 * 64 / 4);
    cvt_kernel<<<(128 * 64 / 4 + 255) / 256, 256, 0, stream>>>(W1r, W1rb, 128 * 64 / 4);

    // ---- layer 1: hb = bf16(relu(mean(agg) @ W1l.T + x @ W1r.T + b1)) ----
    agg64_kernel<<<NN / 4, 256, 0, stream>>>(xb, rowptr, esrc, aggB);
    gemm_mfma_kernel<64, true, true><<<GB, 256, 0, stream>>>(aggB, xb, W1lb, W1rb, b1, hb);

    // ---- layer 2: out = mean(agg2) @ W2l.T + hb @ W2r.T + b2 ----
    agg128_kernel<<<NN / 4, 256, 0, stream>>>(hb, rowptr, esrc, aggB);  // kills xb; last use of esrc/rowptr
    cvt_kernel<<<(128 * 128 / 4 + 255) / 256, 256, 0, stream>>>(W2l, W2lb, 128 * 128 / 4);
    cvt_kernel<<<(128 * 128 / 4 + 255) / 256, 256, 0, stream>>>(W2r, W2rb, 128 * 128 / 4);
    gemm_mfma_kernel<128, false, false><<<GB, 256, 0, stream>>>(aggB, hb, W2lb, W2rb, b2, out);
}